// Round 1
// baseline (712.853 us; speedup 1.0000x reference)
//
#include <hip/hip_runtime.h>
#include <hip/hip_bf16.h>

#define N_CELLS 128
#define C_N     256
#define K_NB    16
#define D_N     64
#define G_N     8
#define HS      128
#define HM      128
#define HMOD    64

// ---------- helpers ----------

__device__ __forceinline__ float rl(float v, int l) {
    // broadcast lane l's value (uniform l) via v_readlane -> SGPR
    return __uint_as_float((unsigned)__builtin_amdgcn_readlane((int)__float_as_uint(v), l));
}

__device__ __forceinline__ unsigned f2bf_bits(float f) {
    unsigned u = __float_as_uint(f);
    u += 0x7fffu + ((u >> 16) & 1u);   // round-nearest-even
    return u >> 16;
}
__device__ __forceinline__ unsigned pack2(float lo, float hi) {
    return f2bf_bits(lo) | (f2bf_bits(hi) << 16);
}
__device__ __forceinline__ void unpack2(unsigned u, float &lo, float &hi) {
    lo = __uint_as_float(u << 16);
    hi = __uint_as_float(u & 0xffff0000u);
}

__device__ __forceinline__ float tanh_fast(float z) {
    // tanh(z) = 1 - 2/(1+exp(2z)); saturates correctly for large |z|
    float e = __expf(2.0f * z);
    return 1.0f - 2.0f / (e + 1.0f);
}

__device__ __forceinline__ float gelu_tanh(float x) {
    // jax.nn.gelu approximate=True (default)
    float z = 0.7978845608028654f * (x + 0.044715f * x * x * x);
    return 0.5f * x * (1.0f + tanh_fast(z));
}

// ---------- kernel 1: per-cell modulation gate ----------
// gate[n,d] = tanh( mod_w2[n]^T tanh( mod_w1[n]^T mean_c h[n,c,:] + mod_b1[n] ) + mod_b2[n] )

__global__ __launch_bounds__(64) void gate_kernel(
    const float* __restrict__ h,
    const float* __restrict__ mod_w1, const float* __restrict__ mod_b1,
    const float* __restrict__ mod_w2, const float* __restrict__ mod_b2,
    float* __restrict__ gate)
{
    int n = blockIdx.x;
    int l = threadIdx.x;           // 0..63
    __shared__ float sh[64];

    const float* hn = h + (size_t)n * C_N * D_N;
    float acc = 0.0f;
    for (int c = 0; c < C_N; ++c) acc += hn[c * D_N + l];
    acc *= (1.0f / C_N);
    sh[l] = acc;
    __syncthreads();

    float a1 = mod_b1[n * HMOD + l];
    for (int d = 0; d < D_N; ++d)
        a1 = fmaf(sh[d], mod_w1[((size_t)n * D_N + d) * HMOD + l], a1);
    float mh = tanh_fast(a1);
    __syncthreads();
    sh[l] = mh;
    __syncthreads();

    float a2 = mod_b2[n * D_N + l];
    for (int q = 0; q < HMOD; ++q)
        a2 = fmaf(sh[q], mod_w2[((size_t)n * HMOD + q) * D_N + l], a2);
    gate[n * D_N + l] = tanh_fast(a2);
}

// ---------- kernel 2: main per-neuron computation ----------
// grid = 256 blocks (2 per cell), 1024 threads = 16 waves, 1 wave handles 8 neurons.
// lane = output dim d (0..63). Weights in LDS as packed bf16 pairs along the
// hidden index: w1pack[f][l] = (w1[2l][f], w1[2l+1][f]); w2pack[i][d] = (w2[d][2i], w2[d][2i+1]).

__global__ __launch_bounds__(1024, 4) void main_kernel(
    const float* __restrict__ h, const float* __restrict__ neuron_id,
    const float* __restrict__ neuron_key,
    const float* __restrict__ state_w1, const float* __restrict__ state_b1,
    const float* __restrict__ state_gs1, const float* __restrict__ state_gb1,
    const float* __restrict__ state_w2, const float* __restrict__ state_b2,
    const float* __restrict__ state_gs2, const float* __restrict__ state_gb2,
    const float* __restrict__ msg_w1, const float* __restrict__ msg_b1,
    const float* __restrict__ msg_gs1, const float* __restrict__ msg_gb1,
    const float* __restrict__ msg_w2, const float* __restrict__ msg_b2,
    const float* __restrict__ msg_gs2, const float* __restrict__ msg_gb2,
    const int* __restrict__ conn_idx, const int* __restrict__ cell_to_group,
    const float* __restrict__ gate, float* __restrict__ out)
{
    __shared__ unsigned w1m[128 * 64];  // msg_w1 packed: 32 KB
    __shared__ unsigned w2m[64 * 64];   // msg_w2 packed (gs2 folded): 16 KB
    __shared__ unsigned w1s[128 * 64];  // state_w1 packed: 32 KB
    __shared__ unsigned w2s[64 * 64];   // state_w2 packed (gs2 folded): 16 KB

    const int tid = threadIdx.x;
    const int nb  = blockIdx.x;     // 0..255
    const int n   = nb >> 1;
    const int g   = cell_to_group[n];

    // ---- stage weights (f32 global -> packed bf16 LDS) ----
    for (int idx = tid; idx < 128 * 64; idx += 1024) {
        int f = idx >> 6, l = idx & 63;
        w1m[idx] = pack2(msg_w1[(2 * l) * (2 * D_N) + f], msg_w1[(2 * l + 1) * (2 * D_N) + f]);
        w1s[idx] = pack2(state_w1[(2 * l) * (2 * D_N) + f], state_w1[(2 * l + 1) * (2 * D_N) + f]);
    }
    for (int idx = tid; idx < 64 * 64; idx += 1024) {
        int i = idx >> 6, d = idx & 63;
        float gm = msg_gs2[g * D_N + d];
        float gs = state_gs2[g * D_N + d];
        w2m[idx] = pack2(msg_w2[d * HM + 2 * i] * gm, msg_w2[d * HM + 2 * i + 1] * gm);
        w2s[idx] = pack2(state_w2[d * HS + 2 * i] * gs, state_w2[d * HS + 2 * i + 1] * gs);
    }
    __syncthreads();

    const int wave = tid >> 6;
    const int lane = tid & 63;

    // ---- per-lane constants (uniform over this block's neurons) ----
    const float mb1lo = msg_b1[2 * lane],            mb1hi = msg_b1[2 * lane + 1];
    const float mgs1lo = msg_gs1[g * HM + 2 * lane], mgs1hi = msg_gs1[g * HM + 2 * lane + 1];
    const float mgb1lo = msg_gb1[g * HM + 2 * lane], mgb1hi = msg_gb1[g * HM + 2 * lane + 1];
    const float mb2f = fmaf(msg_b2[lane], msg_gs2[g * D_N + lane], msg_gb2[g * D_N + lane]);

    const float sb1lo = state_b1[2 * lane],            sb1hi = state_b1[2 * lane + 1];
    const float sgs1lo = state_gs1[g * HS + 2 * lane], sgs1hi = state_gs1[g * HS + 2 * lane + 1];
    const float sgb1lo = state_gb1[g * HS + 2 * lane], sgb1hi = state_gb1[g * HS + 2 * lane + 1];
    const float sb2f = fmaf(state_b2[lane], state_gs2[g * D_N + lane], state_gb2[g * D_N + lane]);

    const float gatev = gate[n * D_N + lane];

    const float* hn  = h         + (size_t)n * C_N * D_N;
    const float* idn = neuron_id + (size_t)n * C_N * D_N;

    const int c0 = (nb & 1) * 128 + wave * 8;

    for (int ci = 0; ci < 8; ++ci) {
        const int c = c0 + ci;
        const float vh = hn[c * D_N + lane];
        const float vq = neuron_key[((size_t)n * C_N + c) * D_N + lane];
        const int   jv = conn_idx[((size_t)n * C_N + c) * K_NB + (lane & 15)];

        // ---- attention logits: per head (lane>>4), dot over 16 dims ----
        float att[16];
        #pragma unroll
        for (int k = 0; k < 16; ++k) {
            int j = __builtin_amdgcn_readlane(jv, k);
            float kid = idn[j * D_N + lane];
            float p = vq * kid;
            p += __shfl_xor(p, 1);
            p += __shfl_xor(p, 2);
            p += __shfl_xor(p, 4);
            p += __shfl_xor(p, 8);
            att[k] = p * 0.25f;   // / sqrt(16)
        }
        // softmax over K (per lane; lanes of a head group hold identical values)
        float mx = att[0];
        #pragma unroll
        for (int k = 1; k < 16; ++k) mx = fmaxf(mx, att[k]);
        float ssum = 0.0f;
        #pragma unroll
        for (int k = 0; k < 16; ++k) { att[k] = __expf(att[k] - mx); ssum += att[k]; }
        const float inv = 1.0f / ssum;
        #pragma unroll
        for (int k = 0; k < 16; ++k) att[k] *= inv;

        // ---- h-half of edge-MLP layer 1 (shared across all 16 edges) ----
        float m1h0 = 0.0f, m1h1 = 0.0f;
        #pragma unroll 8
        for (int f = 0; f < 64; ++f) {
            float w0, w1v; unpack2(w1m[(64 + f) * 64 + lane], w0, w1v);
            float s = rl(vh, f);
            m1h0 = fmaf(s, w0, m1h0);
            m1h1 = fmaf(s, w1v, m1h1);
        }

        float agg = 0.0f;

        #pragma unroll
        for (int kb = 0; kb < 16; kb += 8) {
            // neighbor rows for this batch
            float nbv[8];
            #pragma unroll
            for (int k8 = 0; k8 < 8; ++k8) {
                int j = __builtin_amdgcn_readlane(jv, kb + k8);
                nbv[k8] = hn[j * D_N + lane];
            }
            // layer 1 (neighbor half): a0 -> hh=2*lane, a1 -> hh=2*lane+1
            float a0[8], a1[8];
            #pragma unroll
            for (int k8 = 0; k8 < 8; ++k8) { a0[k8] = 0.0f; a1[k8] = 0.0f; }
            #pragma unroll 4
            for (int f = 0; f < 64; ++f) {
                float w0, w1v; unpack2(w1m[f * 64 + lane], w0, w1v);
                #pragma unroll
                for (int k8 = 0; k8 < 8; ++k8) {
                    float s = rl(nbv[k8], f);
                    a0[k8] = fmaf(s, w0, a0[k8]);
                    a1[k8] = fmaf(s, w1v, a1[k8]);
                }
            }
            // finish layer 1: +h-part, +bias, gelu, per-group gain/bias
            #pragma unroll
            for (int k8 = 0; k8 < 8; ++k8) {
                float y0 = a0[k8] + m1h0 + mb1lo;
                float y1 = a1[k8] + m1h1 + mb1hi;
                a0[k8] = fmaf(gelu_tanh(y0), mgs1lo, mgb1lo);
                a1[k8] = fmaf(gelu_tanh(y1), mgs1hi, mgb1hi);
            }
            // layer 2: m2[d]; gs2 folded into weights
            float m2a[8];
            #pragma unroll
            for (int k8 = 0; k8 < 8; ++k8) m2a[k8] = 0.0f;
            #pragma unroll 4
            for (int i2 = 0; i2 < 64; ++i2) {
                float w0, w1v; unpack2(w2m[i2 * 64 + lane], w0, w1v);
                #pragma unroll
                for (int k8 = 0; k8 < 8; ++k8) {
                    float s0 = rl(a0[k8], i2);
                    float s1 = rl(a1[k8], i2);
                    m2a[k8] = fmaf(s0, w0, fmaf(s1, w1v, m2a[k8]));
                }
            }
            // attention-weighted aggregation
            #pragma unroll
            for (int k8 = 0; k8 < 8; ++k8)
                agg = fmaf(att[kb + k8], m2a[k8] + mb2f, agg);
        }

        // ---- state MLP: s_in = [h, agg] ----
        float sa0 = 0.0f, sa1 = 0.0f;
        #pragma unroll 8
        for (int f = 0; f < 64; ++f) {
            float w0, w1v; unpack2(w1s[f * 64 + lane], w0, w1v);
            float s = rl(vh, f);
            sa0 = fmaf(s, w0, sa0);
            sa1 = fmaf(s, w1v, sa1);
        }
        #pragma unroll 8
        for (int f = 0; f < 64; ++f) {
            float w0, w1v; unpack2(w1s[(64 + f) * 64 + lane], w0, w1v);
            float s = rl(agg, f);
            sa0 = fmaf(s, w0, sa0);
            sa1 = fmaf(s, w1v, sa1);
        }
        float y0 = fmaf(gelu_tanh(sa0 + sb1lo), sgs1lo, sgb1lo);
        float y1 = fmaf(gelu_tanh(sa1 + sb1hi), sgs1hi, sgb1hi);

        float dacc = 0.0f;
        #pragma unroll 8
        for (int i2 = 0; i2 < 64; ++i2) {
            float w0, w1v; unpack2(w2s[i2 * 64 + lane], w0, w1v);
            float s0 = rl(y0, i2);
            float s1 = rl(y1, i2);
            dacc = fmaf(s0, w0, fmaf(s1, w1v, dacc));
        }
        float delta = dacc + sb2f;

        out[((size_t)n * C_N + c) * D_N + lane] = fmaf(gatev, delta, vh);
    }
}

// ---------- launch ----------

extern "C" void kernel_launch(void* const* d_in, const int* in_sizes, int n_in,
                              void* d_out, int out_size, void* d_ws, size_t ws_size,
                              hipStream_t stream) {
    const float* h          = (const float*)d_in[0];
    const float* neuron_id  = (const float*)d_in[1];
    const float* neuron_key = (const float*)d_in[2];
    const float* state_w1   = (const float*)d_in[3];
    const float* state_b1   = (const float*)d_in[4];
    const float* state_gs1  = (const float*)d_in[5];
    const float* state_gb1  = (const float*)d_in[6];
    const float* state_w2   = (const float*)d_in[7];
    const float* state_b2   = (const float*)d_in[8];
    const float* state_gs2  = (const float*)d_in[9];
    const float* state_gb2  = (const float*)d_in[10];
    const float* msg_w1     = (const float*)d_in[11];
    const float* msg_b1     = (const float*)d_in[12];
    const float* msg_gs1    = (const float*)d_in[13];
    const float* msg_gb1    = (const float*)d_in[14];
    const float* msg_w2     = (const float*)d_in[15];
    const float* msg_b2     = (const float*)d_in[16];
    const float* msg_gs2    = (const float*)d_in[17];
    const float* msg_gb2    = (const float*)d_in[18];
    const float* mod_w1     = (const float*)d_in[19];
    const float* mod_b1     = (const float*)d_in[20];
    const float* mod_w2     = (const float*)d_in[21];
    const float* mod_b2     = (const float*)d_in[22];
    const int*   conn_idx   = (const int*)d_in[23];
    const int*   c2g        = (const int*)d_in[24];

    float* gate = (float*)d_ws;   // 128*64 f32 = 32 KB scratch
    float* outp = (float*)d_out;

    gate_kernel<<<dim3(N_CELLS), dim3(64), 0, stream>>>(h, mod_w1, mod_b1, mod_w2, mod_b2, gate);

    main_kernel<<<dim3(256), dim3(1024), 0, stream>>>(
        h, neuron_id, neuron_key,
        state_w1, state_b1, state_gs1, state_gb1,
        state_w2, state_b2, state_gs2, state_gb2,
        msg_w1, msg_b1, msg_gs1, msg_gb1,
        msg_w2, msg_b2, msg_gs2, msg_gb2,
        conn_idx, c2g, gate, outp);
}

// Round 2
// 176.380 us; speedup vs baseline: 4.0416x; 4.0416x over previous
//
#include <hip/hip_runtime.h>
#include <hip/hip_bf16.h>

#define N_CELLS 128
#define C_N     256
#define K_NB    16
#define D_N     64
#define G_N     8
#define HS      128
#define HM      128
#define HMOD    64

typedef __bf16 bf16x8 __attribute__((ext_vector_type(8)));
typedef float  f32x4v __attribute__((ext_vector_type(4)));

// ---------- helpers ----------

__device__ __forceinline__ unsigned cvtpk(float lo, float hi) {
    __hip_bfloat162 t = __float22bfloat162_rn(float2{lo, hi});
    return *reinterpret_cast<unsigned*>(&t);
}

__device__ __forceinline__ f32x4v mfma16(uint4 a, uint4 b, f32x4v c) {
    return __builtin_amdgcn_mfma_f32_16x16x32_bf16(
        __builtin_bit_cast(bf16x8, a), __builtin_bit_cast(bf16x8, b), c, 0, 0, 0);
}

__device__ __forceinline__ uint4 lds_frag(const void* base, int byte_off) {
    return *reinterpret_cast<const uint4*>(reinterpret_cast<const char*>(base) + byte_off);
}

__device__ __forceinline__ float gelu_f(float x) {
    // exact tanh-gelu: 0.5x(1+tanh(0.79788456(x+0.044715x^3))) = x - x/(1+exp(2z))
    float x2 = x * x;
    float u  = x * fmaf(x2, 0.044715f, 1.0f);
    float e  = __expf(1.5957691216057308f * u);
    float r  = __builtin_amdgcn_rcpf(e + 1.0f);
    return x - x * r;
}

__device__ __forceinline__ float tanh_fast(float z) {
    float e = __expf(2.0f * z);
    return 1.0f - 2.0f / (e + 1.0f);
}

// fold gains into w2-style B-fragments:  wf = gs2[d] * w2[d][k] * gs1[k]
// c2[nb] = gs2[d]*(sum_k w2[d][k]*gb1[k] + b2[d]) + gb2[d]
__device__ __forceinline__ void load_w2_folded(
    const float* __restrict__ w2, const float* __restrict__ gs1,
    const float* __restrict__ gb1, const float* __restrict__ gs2,
    const float* __restrict__ b2, const float* __restrict__ gb2,
    int g, int lrow, int lgrp, uint4 wf[4][4], float c2[4])
{
    #pragma unroll
    for (int nb2 = 0; nb2 < 4; ++nb2) {
        int d = nb2 * 16 + lrow;
        float gs2d = gs2[g * 64 + d];
        float cgb = 0.0f;
        #pragma unroll
        for (int kf = 0; kf < 4; ++kf) {
            int k0 = kf * 32 + lgrp * 8;
            const float* wp = w2 + d * 128 + k0;
            float4 wa = *(const float4*)wp, wb = *(const float4*)(wp + 4);
            const float* gp = gs1 + g * 128 + k0;
            float4 ga = *(const float4*)gp, gbv = *(const float4*)(gp + 4);
            const float* bp = gb1 + g * 128 + k0;
            float4 ba = *(const float4*)bp, bbv = *(const float4*)(bp + 4);
            cgb += wa.x*ba.x + wa.y*ba.y + wa.z*ba.z + wa.w*ba.w
                 + wb.x*bbv.x + wb.y*bbv.y + wb.z*bbv.z + wb.w*bbv.w;
            wf[nb2][kf] = make_uint4(
                cvtpk(wa.x*ga.x*gs2d,  wa.y*ga.y*gs2d),
                cvtpk(wa.z*ga.z*gs2d,  wa.w*ga.w*gs2d),
                cvtpk(wb.x*gbv.x*gs2d, wb.y*gbv.y*gs2d),
                cvtpk(wb.z*gbv.z*gs2d, wb.w*gbv.w*gs2d));
        }
        cgb += __shfl_xor(cgb, 16);
        cgb += __shfl_xor(cgb, 32);
        c2[nb2] = fmaf(gs2d, cgb + b2[d], gb2[g * 64 + d]);
    }
}

// ---------- kernel 1: per-cell modulation gate (verified in R1) ----------

__global__ __launch_bounds__(64) void gate_kernel(
    const float* __restrict__ h,
    const float* __restrict__ mod_w1, const float* __restrict__ mod_b1,
    const float* __restrict__ mod_w2, const float* __restrict__ mod_b2,
    float* __restrict__ gate)
{
    int n = blockIdx.x;
    int l = threadIdx.x;
    __shared__ float sh[64];

    const float* hn = h + (size_t)n * C_N * D_N;
    float acc = 0.0f;
    for (int c = 0; c < C_N; ++c) acc += hn[c * D_N + l];
    acc *= (1.0f / C_N);
    sh[l] = acc;
    __syncthreads();

    float a1 = mod_b1[n * HMOD + l];
    for (int d = 0; d < D_N; ++d)
        a1 = fmaf(sh[d], mod_w1[((size_t)n * D_N + d) * HMOD + l], a1);
    float mh = tanh_fast(a1);
    __syncthreads();
    sh[l] = mh;
    __syncthreads();

    float a2 = mod_b2[n * D_N + l];
    for (int q = 0; q < HMOD; ++q)
        a2 = fmaf(sh[q], mod_w2[((size_t)n * HMOD + q) * D_N + l], a2);
    gate[n * D_N + l] = tanh_fast(a2);
}

// ---------- kernel 2: MFMA main ----------
// 256 blocks = 2 per cell (128 neurons each), 512 threads = 8 waves, 16 neurons/wave.
// All LDS 2D tiles use XOR swizzle: byte_in_row ^= ((row&7)<<4).

#define SWZ(row, b) ((b) ^ (((row) & 7) << 4))

__global__ __launch_bounds__(512, 2) void main_kernel(
    const float* __restrict__ h, const float* __restrict__ neuron_id,
    const float* __restrict__ neuron_key,
    const float* __restrict__ state_w1, const float* __restrict__ state_b1,
    const float* __restrict__ state_gs1, const float* __restrict__ state_gb1,
    const float* __restrict__ state_w2, const float* __restrict__ state_b2,
    const float* __restrict__ state_gs2, const float* __restrict__ state_gb2,
    const float* __restrict__ msg_w1, const float* __restrict__ msg_b1,
    const float* __restrict__ msg_gs1, const float* __restrict__ msg_gb1,
    const float* __restrict__ msg_w2, const float* __restrict__ msg_b2,
    const float* __restrict__ msg_gs2, const float* __restrict__ msg_gb2,
    const int* __restrict__ conn_idx, const int* __restrict__ cell_to_group,
    const float* __restrict__ gate, float* __restrict__ out)
{
    __shared__ __align__(16) unsigned short hc[C_N * D_N];        // [256][64] bf16, 128B rows, swz
    __shared__ __align__(16) unsigned short w1m_l[HM * 128];      // [128][128] bf16, 256B rows, swz
    __shared__ __align__(16) unsigned short sbuf_all[8 * 2 * 16 * 128]; // per wave per u: [16][128] swz
    __shared__ __align__(16) unsigned short aggbuf_all[8 * 16 * 64];    // per wave: [16][64] swz
    __shared__ float attbuf_all[8 * 2 * 64];                      // per wave per u: [head][edge]
    __shared__ float b1m_l[HM], b1s_l[HS];

    const int tid = threadIdx.x;
    const int bid = blockIdx.x;
    const int n = bid >> 1;
    const int g = cell_to_group[n];

    // ---- stage h (f32 -> bf16 swizzled LDS) ----
    const float* hn = h + (size_t)n * C_N * D_N;
    for (int idx = tid; idx < 2048; idx += 512) {       // 2048 16B chunks
        int row = idx >> 3, ch = idx & 7;
        const float4* src = reinterpret_cast<const float4*>(hn + row * 64 + ch * 8);
        float4 a = src[0], b = src[1];
        uint4 p = make_uint4(cvtpk(a.x, a.y), cvtpk(a.z, a.w), cvtpk(b.x, b.y), cvtpk(b.z, b.w));
        int byte = row * 128 + SWZ(row, ch * 16);
        *reinterpret_cast<uint4*>(reinterpret_cast<char*>(hc) + byte) = p;
    }
    // ---- stage msg_w1 ----
    for (int idx = tid; idx < 2048; idx += 512) {       // 128 rows x 16 chunks
        int row = idx >> 4, ch = idx & 15;
        const float4* src = reinterpret_cast<const float4*>(msg_w1 + row * 128 + ch * 8);
        float4 a = src[0], b = src[1];
        uint4 p = make_uint4(cvtpk(a.x, a.y), cvtpk(a.z, a.w), cvtpk(b.x, b.y), cvtpk(b.z, b.w));
        int byte = row * 256 + SWZ(row, ch * 16);
        *reinterpret_cast<uint4*>(reinterpret_cast<char*>(w1m_l) + byte) = p;
    }
    if (tid < 128) { b1m_l[tid] = msg_b1[tid]; b1s_l[tid] = state_b1[tid]; }
    __syncthreads();

    const int wave = tid >> 6, lane = tid & 63;
    const int lrow = lane & 15, lgrp = lane >> 4;
    unsigned short* sbufW = sbuf_all + wave * (2 * 16 * 128);
    unsigned short* aggb  = aggbuf_all + wave * (16 * 64);
    float* attb = attbuf_all + wave * 128;
    const int cg0 = (bid & 1) * 128 + wave * 16;

    // ---- msg w2 folded fragments (resident) ----
    uint4 w2f[4][4];
    float mb2c[4];
    load_w2_folded(msg_w2, msg_gs1, msg_gb1, msg_gs2, msg_b2, msg_gb2,
                   g, lrow, lgrp, w2f, mb2c);

    // ================= edge phase: 8 pairs of neurons =================
    #pragma unroll 1
    for (int pi = 0; pi < 8; ++pi) {
        int jv0 = 0, jv1 = 0;
        // ---- attention: lane = (edge=lrow, head=lgrp) ----
        #pragma unroll
        for (int u = 0; u < 2; ++u) {
            int c = cg0 + pi * 2 + u;
            int jv = conn_idx[((size_t)n * C_N + c) * K_NB + lrow];
            if (u == 0) jv0 = jv; else jv1 = jv;
            const float* kp = neuron_id + (size_t)n * C_N * D_N + jv * 64 + lgrp * 16;
            const float* qp = neuron_key + ((size_t)n * C_N + c) * 64 + lgrp * 16;
            float4 k0 = *(const float4*)kp,     k1 = *(const float4*)(kp + 4),
                   k2 = *(const float4*)(kp + 8), k3 = *(const float4*)(kp + 12);
            float4 q0 = *(const float4*)qp,     q1 = *(const float4*)(qp + 4),
                   q2 = *(const float4*)(qp + 8), q3 = *(const float4*)(qp + 12);
            float dt = k0.x*q0.x + k0.y*q0.y + k0.z*q0.z + k0.w*q0.w
                     + k1.x*q1.x + k1.y*q1.y + k1.z*q1.z + k1.w*q1.w
                     + k2.x*q2.x + k2.y*q2.y + k2.z*q2.z + k2.w*q2.w
                     + k3.x*q3.x + k3.y*q3.y + k3.z*q3.z + k3.w*q3.w;
            float lg = dt * 0.25f;
            float mx = lg;
            mx = fmaxf(mx, __shfl_xor(mx, 1));
            mx = fmaxf(mx, __shfl_xor(mx, 2));
            mx = fmaxf(mx, __shfl_xor(mx, 4));
            mx = fmaxf(mx, __shfl_xor(mx, 8));
            float ex = __expf(lg - mx);
            float sm = ex;
            sm += __shfl_xor(sm, 1);
            sm += __shfl_xor(sm, 2);
            sm += __shfl_xor(sm, 4);
            sm += __shfl_xor(sm, 8);
            attb[u * 64 + lgrp * 16 + lrow] = ex * __builtin_amdgcn_rcpf(sm);
        }

        // ---- L1 B-fragments: x^T (gathered neighbor + self), per u ----
        uint4 xf[2][4];
        #pragma unroll
        for (int u = 0; u < 2; ++u) {
            int jr = (u == 0) ? jv0 : jv1;
            int cs = cg0 + pi * 2 + u;
            #pragma unroll
            for (int kf = 0; kf < 2; ++kf) {
                int byte = jr * 128 + SWZ(jr, kf * 64 + lgrp * 16);
                xf[u][kf] = lds_frag(hc, byte);
            }
            #pragma unroll
            for (int kf = 2; kf < 4; ++kf) {
                int byte = cs * 128 + SWZ(cs, (kf - 2) * 64 + lgrp * 16);
                xf[u][kf] = lds_frag(hc, byte);
            }
        }

        // ---- L1 GEMM (swapped: A = msg_w1 rows=hidden, B = x^T cols=edge) ----
        unsigned short* sb0 = sbufW;            // u=0 m1g [16 edge][128]
        unsigned short* sb1 = sbufW + 16 * 128; // u=1
        for (int nbM = 0; nbM < 8; ++nbM) {
            int wrow = nbM * 16 + lrow;
            uint4 wA[4];
            #pragma unroll
            for (int kf = 0; kf < 4; ++kf)
                wA[kf] = lds_frag(w1m_l, wrow * 256 + SWZ(wrow, kf * 64 + lgrp * 16));
            f32x4v acc0 = {0.f, 0.f, 0.f, 0.f}, acc1 = {0.f, 0.f, 0.f, 0.f};
            #pragma unroll
            for (int kf = 0; kf < 4; ++kf) {
                acc0 = mfma16(wA[kf], xf[0][kf], acc0);
                acc1 = mfma16(wA[kf], xf[1][kf], acc1);
            }
            // finish: gelu(acc + b1) -> bf16 quad -> transpose-write sbuf[edge][hidden]
            float4 b1q = *reinterpret_cast<const float4*>(&b1m_l[nbM * 16 + lgrp * 4]);
            {
                float g0 = gelu_f(acc0[0] + b1q.x), g1 = gelu_f(acc0[1] + b1q.y);
                float g2 = gelu_f(acc0[2] + b1q.z), g3 = gelu_f(acc0[3] + b1q.w);
                uint2 pk = make_uint2(cvtpk(g0, g1), cvtpk(g2, g3));
                int byte = lrow * 256 + SWZ(lrow, nbM * 32 + lgrp * 8);
                *reinterpret_cast<uint2*>(reinterpret_cast<char*>(sb0) + byte) = pk;
            }
            {
                float g0 = gelu_f(acc1[0] + b1q.x), g1 = gelu_f(acc1[1] + b1q.y);
                float g2 = gelu_f(acc1[2] + b1q.z), g3 = gelu_f(acc1[3] + b1q.w);
                uint2 pk = make_uint2(cvtpk(g0, g1), cvtpk(g2, g3));
                int byte = lrow * 256 + SWZ(lrow, nbM * 32 + lgrp * 8);
                *reinterpret_cast<uint2*>(reinterpret_cast<char*>(sb1) + byte) = pk;
            }
        }

        // ---- L2 GEMM + attention-weighted aggregation, per u ----
        #pragma unroll
        for (int u = 0; u < 2; ++u) {
            unsigned short* sb = (u == 0) ? sb0 : sb1;
            uint4 mA[4];
            #pragma unroll
            for (int kf = 0; kf < 4; ++kf)
                mA[kf] = lds_frag(sb, lrow * 256 + SWZ(lrow, kf * 64 + lgrp * 16));
            int ni = pi * 2 + u;
            #pragma unroll
            for (int nb2 = 0; nb2 < 4; ++nb2) {
                f32x4v a2 = {0.f, 0.f, 0.f, 0.f};
                #pragma unroll
                for (int kf = 0; kf < 4; ++kf)
                    a2 = mfma16(mA[kf], w2f[nb2][kf], a2);
                float4 aw = *reinterpret_cast<const float4*>(&attb[u * 64 + nb2 * 16 + lgrp * 4]);
                float part = aw.x * a2[0] + aw.y * a2[1] + aw.z * a2[2] + aw.w * a2[3];
                part += __shfl_xor(part, 16);
                part += __shfl_xor(part, 32);
                float aggv = part + mb2c[nb2];
                if (lgrp == nb2) {
                    int byte = ni * 128 + SWZ(ni, (nb2 * 16 + lrow) * 2);
                    *reinterpret_cast<unsigned short*>(reinterpret_cast<char*>(aggb) + byte) =
                        (unsigned short)(cvtpk(aggv, 0.f) & 0xffffu);
                }
            }
        }
    }

    // ================= state phase (16 neurons per wave) =================
    // S1 (swapped): A = state_w1 (global f32->bf16), B = [h | agg] cols=neuron
    uint4 sB[4];
    {
        int hr = cg0 + lrow;
        sB[0] = lds_frag(hc, hr * 128 + SWZ(hr, lgrp * 16));
        sB[1] = lds_frag(hc, hr * 128 + SWZ(hr, 64 + lgrp * 16));
        sB[2] = lds_frag(aggb, lrow * 128 + SWZ(lrow, lgrp * 16));
        sB[3] = lds_frag(aggb, lrow * 128 + SWZ(lrow, 64 + lgrp * 16));
    }
    unsigned short* s1b = sbufW;   // reuse: s1g [16 neuron][128]
    for (int nbM = 0; nbM < 8; ++nbM) {
        uint4 wA[4];
        #pragma unroll
        for (int kf = 0; kf < 4; ++kf) {
            const float* wp = state_w1 + (size_t)(nbM * 16 + lrow) * 128 + kf * 32 + lgrp * 8;
            float4 a = *(const float4*)wp, b = *(const float4*)(wp + 4);
            wA[kf] = make_uint4(cvtpk(a.x, a.y), cvtpk(a.z, a.w), cvtpk(b.x, b.y), cvtpk(b.z, b.w));
        }
        f32x4v acc = {0.f, 0.f, 0.f, 0.f};
        #pragma unroll
        for (int kf = 0; kf < 4; ++kf)
            acc = mfma16(wA[kf], sB[kf], acc);
        float4 b1q = *reinterpret_cast<const float4*>(&b1s_l[nbM * 16 + lgrp * 4]);
        float g0 = gelu_f(acc[0] + b1q.x), g1 = gelu_f(acc[1] + b1q.y);
        float g2 = gelu_f(acc[2] + b1q.z), g3 = gelu_f(acc[3] + b1q.w);
        uint2 pk = make_uint2(cvtpk(g0, g1), cvtpk(g2, g3));
        int byte = lrow * 256 + SWZ(lrow, nbM * 32 + lgrp * 8);
        *reinterpret_cast<uint2*>(reinterpret_cast<char*>(s1b) + byte) = pk;
    }

    // S2: A = s1g rows=neuron, B = folded state_w2 cols=d
    uint4 w2sf[4][4];
    float sb2c[4];
    load_w2_folded(state_w2, state_gs1, state_gb1, state_gs2, state_b2, state_gb2,
                   g, lrow, lgrp, w2sf, sb2c);
    uint4 s1A[4];
    #pragma unroll
    for (int kf = 0; kf < 4; ++kf)
        s1A[kf] = lds_frag(s1b, lrow * 256 + SWZ(lrow, kf * 64 + lgrp * 16));
    #pragma unroll
    for (int nb2 = 0; nb2 < 4; ++nb2) {
        f32x4v acc = {0.f, 0.f, 0.f, 0.f};
        #pragma unroll
        for (int kf = 0; kf < 4; ++kf)
            acc = mfma16(s1A[kf], w2sf[nb2][kf], acc);
        int d = nb2 * 16 + lrow;
        float gatev = gate[n * 64 + d];
        #pragma unroll
        for (int r = 0; r < 4; ++r) {
            int c = cg0 + lgrp * 4 + r;
            float delta = acc[r] + sb2c[nb2];
            size_t off = ((size_t)n * C_N + c) * 64 + d;
            out[off] = fmaf(gatev, delta, h[off]);
        }
    }
}

// ---------- launch ----------

extern "C" void kernel_launch(void* const* d_in, const int* in_sizes, int n_in,
                              void* d_out, int out_size, void* d_ws, size_t ws_size,
                              hipStream_t stream) {
    (void)in_sizes; (void)n_in; (void)out_size; (void)ws_size;
    const float* h          = (const float*)d_in[0];
    const float* neuron_id  = (const float*)d_in[1];
    const float* neuron_key = (const float*)d_in[2];
    const float* state_w1   = (const float*)d_in[3];
    const float* state_b1   = (const float*)d_in[4];
    const float* state_gs1  = (const float*)d_in[5];
    const float* state_gb1  = (const float*)d_in[6];
    const float* state_w2   = (const float*)d_in[7];
    const float* state_b2   = (const float*)d_in[8];
    const float* state_gs2  = (const float*)d_in[9];
    const float* state_gb2  = (const float*)d_in[10];
    const float* msg_w1     = (const float*)d_in[11];
    const float* msg_b1     = (const float*)d_in[12];
    const float* msg_gs1    = (const float*)d_in[13];
    const float* msg_gb1    = (const float*)d_in[14];
    const float* msg_w2     = (const float*)d_in[15];
    const float* msg_b2     = (const float*)d_in[16];
    const float* msg_gs2    = (const float*)d_in[17];
    const float* msg_gb2    = (const float*)d_in[18];
    const float* mod_w1     = (const float*)d_in[19];
    const float* mod_b1     = (const float*)d_in[20];
    const float* mod_w2     = (const float*)d_in[21];
    const float* mod_b2     = (const float*)d_in[22];
    const int*   conn_idx   = (const int*)d_in[23];
    const int*   c2g        = (const int*)d_in[24];

    float* gatep = (float*)d_ws;   // 128*64 f32 = 32 KB scratch
    float* outp  = (float*)d_out;

    gate_kernel<<<dim3(N_CELLS), dim3(64), 0, stream>>>(h, mod_w1, mod_b1, mod_w2, mod_b2, gatep);

    main_kernel<<<dim3(256), dim3(512), 0, stream>>>(
        h, neuron_id, neuron_key,
        state_w1, state_b1, state_gs1, state_gb1,
        state_w2, state_b2, state_gs2, state_gb2,
        msg_w1, msg_b1, msg_gs1, msg_gb1,
        msg_w2, msg_b2, msg_gs2, msg_gb2,
        conn_idx, c2g, gatep, outp);
}

// Round 3
// 168.602 us; speedup vs baseline: 4.2280x; 1.0461x over previous
//
#include <hip/hip_runtime.h>
#include <hip/hip_bf16.h>

#define N_CELLS 128
#define C_N     256
#define K_NB    16
#define D_N     64
#define G_N     8
#define HS      128
#define HM      128
#define HMOD    64

typedef __bf16 bf16x8 __attribute__((ext_vector_type(8)));
typedef float  f32x4v __attribute__((ext_vector_type(4)));

// ---------- helpers ----------

__device__ __forceinline__ float rl(float v, int l) {
    return __uint_as_float((unsigned)__builtin_amdgcn_readlane((int)__float_as_uint(v), l));
}

__device__ __forceinline__ unsigned cvtpk(float lo, float hi) {
    __hip_bfloat162 t = __float22bfloat162_rn(float2{lo, hi});
    return *reinterpret_cast<unsigned*>(&t);
}

__device__ __forceinline__ unsigned short f2bf(float f) {
    return (unsigned short)(cvtpk(f, 0.f) & 0xffffu);
}

__device__ __forceinline__ float bflo(unsigned u) { return __uint_as_float(u << 16); }
__device__ __forceinline__ float bfhi(unsigned u) { return __uint_as_float(u & 0xffff0000u); }

__device__ __forceinline__ f32x4v mfma16(uint4 a, uint4 b, f32x4v c) {
    return __builtin_amdgcn_mfma_f32_16x16x32_bf16(
        __builtin_bit_cast(bf16x8, a), __builtin_bit_cast(bf16x8, b), c, 0, 0, 0);
}

__device__ __forceinline__ float gelu_f(float x) {
    float x2 = x * x;
    float u  = x * fmaf(x2, 0.044715f, 1.0f);
    float e  = __expf(1.5957691216057308f * u);
    float r  = __builtin_amdgcn_rcpf(e + 1.0f);
    return x - x * r;
}

__device__ __forceinline__ float tanh_fast(float z) {
    float e = __expf(2.0f * z);
    return 1.0f - 2.0f / (e + 1.0f);
}

__device__ __forceinline__ uint4 packf8(const float* p) {
    float4 a = *(const float4*)p, b = *(const float4*)(p + 4);
    return make_uint4(cvtpk(a.x, a.y), cvtpk(a.z, a.w), cvtpk(b.x, b.y), cvtpk(b.z, b.w));
}

// wf = gs2[d] * w2[d][k] * gs1[k];  c2 = gs2*(w2.gb1 + b2) + gb2   (verified R2)
__device__ __forceinline__ void load_w2_folded(
    const float* __restrict__ w2, const float* __restrict__ gs1,
    const float* __restrict__ gb1, const float* __restrict__ gs2,
    const float* __restrict__ b2, const float* __restrict__ gb2,
    int g, int lrow, int lgrp, uint4 wf[4][4], float c2[4])
{
    #pragma unroll
    for (int nb2 = 0; nb2 < 4; ++nb2) {
        int d = nb2 * 16 + lrow;
        float gs2d = gs2[g * 64 + d];
        float cgb = 0.0f;
        #pragma unroll
        for (int kf = 0; kf < 4; ++kf) {
            int k0 = kf * 32 + lgrp * 8;
            const float* wp = w2 + d * 128 + k0;
            float4 wa = *(const float4*)wp, wb = *(const float4*)(wp + 4);
            const float* gp = gs1 + g * 128 + k0;
            float4 ga = *(const float4*)gp, gbv = *(const float4*)(gp + 4);
            const float* bp = gb1 + g * 128 + k0;
            float4 ba = *(const float4*)bp, bbv = *(const float4*)(bp + 4);
            cgb += wa.x*ba.x + wa.y*ba.y + wa.z*ba.z + wa.w*ba.w
                 + wb.x*bbv.x + wb.y*bbv.y + wb.z*bbv.z + wb.w*bbv.w;
            wf[nb2][kf] = make_uint4(
                cvtpk(wa.x*ga.x*gs2d,  wa.y*ga.y*gs2d),
                cvtpk(wa.z*ga.z*gs2d,  wa.w*ga.w*gs2d),
                cvtpk(wb.x*gbv.x*gs2d, wb.y*gbv.y*gs2d),
                cvtpk(wb.z*gbv.z*gs2d, wb.w*gbv.w*gs2d));
        }
        cgb += __shfl_xor(cgb, 16);
        cgb += __shfl_xor(cgb, 32);
        c2[nb2] = fmaf(gs2d, cgb + b2[d], gb2[g * 64 + d]);
    }
}

// ---------- kernel 1: per-cell modulation gate ----------

__global__ __launch_bounds__(1024) void gate_kernel(
    const float* __restrict__ h,
    const float* __restrict__ mod_w1, const float* __restrict__ mod_b1,
    const float* __restrict__ mod_w2, const float* __restrict__ mod_b2,
    float* __restrict__ gatep)
{
    __shared__ float red[16][64];
    __shared__ float pooled[64];
    __shared__ float mh[64];
    int n = blockIdx.x, tid = threadIdx.x;
    int d = tid & 63, part = tid >> 6;
    const float* hn = h + (size_t)n * C_N * 64;
    float acc = 0.0f;
    #pragma unroll 4
    for (int i = 0; i < 16; ++i) acc += hn[(part * 16 + i) * 64 + d];
    red[part][d] = acc;
    __syncthreads();
    if (tid < 64) {
        float s = 0.0f;
        #pragma unroll
        for (int p = 0; p < 16; ++p) s += red[p][d];
        pooled[d] = s * (1.0f / 256.0f);
    }
    __syncthreads();
    if (tid < 64) {
        float a1 = mod_b1[n * HMOD + d];
        for (int q = 0; q < 64; ++q)
            a1 = fmaf(pooled[q], mod_w1[((size_t)n * 64 + q) * HMOD + d], a1);
        mh[d] = tanh_fast(a1);
    }
    __syncthreads();
    if (tid < 64) {
        float a2 = mod_b2[n * 64 + d];
        for (int q = 0; q < HMOD; ++q)
            a2 = fmaf(mh[q], mod_w2[((size_t)n * HMOD + q) * 64 + d], a2);
        gatep[n * 64 + d] = tanh_fast(a2);
    }
}

// ---------- kernel 2: per-node projections y = w1n.h, beffpb = w1h.h + b1 ----------
// 256 blocks (half-cell), 512 thr = 8 waves x 16 neurons. Swapped GEMM:
// A = msg_w1 rows (256 outs: 0-127 -> y via cols 0:64, 128-255 -> beff via cols 64:128),
// B = h cols=c (K=64). C transposed via per-wave LDS, coalesced global write.

__global__ __launch_bounds__(512, 4) void node_kernel(
    const float* __restrict__ h, const float* __restrict__ msg_w1,
    const float* __restrict__ msg_b1,
    unsigned short* __restrict__ yws, unsigned short* __restrict__ bews)
{
    __shared__ __align__(16) unsigned short ybuf_all[8][16 * 256];  // 8KB/wave
    int tid = threadIdx.x, bid = blockIdx.x;
    int n = bid >> 1;
    int wave = tid >> 6, lane = tid & 63;
    int lrow = lane & 15, lgrp = lane >> 4;
    int c0 = (bid & 1) * 128 + wave * 16;
    unsigned short* ybuf = ybuf_all[wave];

    uint4 bf[2];
    {
        const float* hp = h + ((size_t)n * C_N + (c0 + lrow)) * 64;
        bf[0] = packf8(hp + lgrp * 8);
        bf[1] = packf8(hp + 32 + lgrp * 8);
    }
    for (int nbM = 0; nbM < 16; ++nbM) {
        int o = nbM * 16 + lrow;
        uint4 af[2];
        #pragma unroll
        for (int kf = 0; kf < 2; ++kf) {
            int k = kf * 32 + lgrp * 8;
            const float* wp = (o < 128) ? (msg_w1 + (size_t)o * 128 + k)
                                        : (msg_w1 + (size_t)(o - 128) * 128 + 64 + k);
            af[kf] = packf8(wp);
        }
        f32x4v acc = {0.f, 0.f, 0.f, 0.f};
        acc = mfma16(af[0], bf[0], acc);
        acc = mfma16(af[1], bf[1], acc);
        float4 addv = {0.f, 0.f, 0.f, 0.f};
        if (nbM >= 8) addv = *(const float4*)(msg_b1 + (nbM - 8) * 16 + lgrp * 4);
        uint2 pk = make_uint2(cvtpk(acc[0] + addv.x, acc[1] + addv.y),
                              cvtpk(acc[2] + addv.z, acc[3] + addv.w));
        int byte = lrow * 512 + ((nbM * 32 + lgrp * 8) ^ ((lrow & 7) << 4));
        *reinterpret_cast<uint2*>(reinterpret_cast<char*>(ybuf) + byte) = pk;
    }
    #pragma unroll
    for (int pass = 0; pass < 8; ++pass) {
        int idx = pass * 64 + lane;
        int row = idx >> 5, col = idx & 31;
        int byte = row * 512 + ((col * 16) ^ ((row & 7) << 4));
        uint4 v = *reinterpret_cast<const uint4*>(reinterpret_cast<const char*>(ybuf) + byte);
        size_t rb = (((size_t)n * C_N + c0 + row) * 128) * 2;
        if (col < 16)
            *reinterpret_cast<uint4*>(reinterpret_cast<char*>(yws) + rb + col * 16) = v;
        else
            *reinterpret_cast<uint4*>(reinterpret_cast<char*>(bews) + rb + (col - 16) * 16) = v;
    }
}

// ---------- kernel 3: attention weights ----------
// 512 blocks x 256 thr (4 waves x 16 neurons). lane = (k=lane&15, t=lane>>4).
// attw layout [g][t*16+k] f32.

__global__ __launch_bounds__(256, 4) void att_kernel(
    const float* __restrict__ neuron_id, const float* __restrict__ neuron_key,
    const int* __restrict__ conn_idx, float* __restrict__ attw)
{
    int tid = threadIdx.x, bid = blockIdx.x;
    int wave = tid >> 6, lane = tid & 63;
    int lrow = lane & 15, t = lane >> 4;
    int base = bid * 64 + wave * 16;

    for (int i = 0; i < 16; ++i) {
        int gidx = base + i;
        int jv = conn_idx[(size_t)gidx * 16 + lrow];
        const float* kp = neuron_id + ((size_t)(gidx & ~255) + jv) * 64 + t * 16;
        const float* qp = neuron_key + (size_t)gidx * 64 + t * 16;
        float4 k0 = *(const float4*)kp,       k1 = *(const float4*)(kp + 4),
               k2 = *(const float4*)(kp + 8), k3 = *(const float4*)(kp + 12);
        float4 q0 = *(const float4*)qp,       q1 = *(const float4*)(qp + 4),
               q2 = *(const float4*)(qp + 8), q3 = *(const float4*)(qp + 12);
        float dt = k0.x*q0.x + k0.y*q0.y + k0.z*q0.z + k0.w*q0.w
                 + k1.x*q1.x + k1.y*q1.y + k1.z*q1.z + k1.w*q1.w
                 + k2.x*q2.x + k2.y*q2.y + k2.z*q2.z + k2.w*q2.w
                 + k3.x*q3.x + k3.y*q3.y + k3.z*q3.z + k3.w*q3.w;
        float lg = dt * 0.25f;
        float mx = lg;
        mx = fmaxf(mx, __shfl_xor(mx, 1));
        mx = fmaxf(mx, __shfl_xor(mx, 2));
        mx = fmaxf(mx, __shfl_xor(mx, 4));
        mx = fmaxf(mx, __shfl_xor(mx, 8));
        float ex = __expf(lg - mx);
        float sm = ex;
        sm += __shfl_xor(sm, 1);
        sm += __shfl_xor(sm, 2);
        sm += __shfl_xor(sm, 4);
        sm += __shfl_xor(sm, 8);
        attw[(size_t)gidx * 64 + lane] = ex * __builtin_amdgcn_rcpf(sm);
    }
}

// ---------- kernel 4: edge phase ----------
// 512 blocks x 256 thr (4 waves x 16 neurons; block = 64 neurons of one cell).
// Per neuron: gather y[j] (coalesced 256B), z = y + beffpb, gelu, attn-weighted
// accumulate p[t] (lane = dims 2l,2l+1). Then per 16-neuron batch: L2 via mfma
// with folded w2, agg -> ws (bf16) through LDS transpose.

__global__ __launch_bounds__(256, 2) void edge_kernel(
    const unsigned short* __restrict__ yws, const unsigned short* __restrict__ bews,
    const float* __restrict__ attw, const int* __restrict__ conn_idx,
    const float* __restrict__ msg_w2, const float* __restrict__ msg_gs1,
    const float* __restrict__ msg_gb1, const float* __restrict__ msg_gs2,
    const float* __restrict__ msg_b2, const float* __restrict__ msg_gb2,
    const int* __restrict__ cell_to_group,
    unsigned short* __restrict__ aggws)
{
    __shared__ __align__(16) unsigned short pbuf_all[4][4 * 16 * 128];  // 16KB/wave
    __shared__ __align__(16) unsigned short aggT_all[4][16 * 64];       // 2KB/wave
    int tid = threadIdx.x, bid = blockIdx.x;
    int wave = tid >> 6, lane = tid & 63;
    int lrow = lane & 15, lgrp = lane >> 4;
    int base = bid * 64 + wave * 16;
    int n = base >> 8;
    int g = cell_to_group[n];
    unsigned short* pbuf = pbuf_all[wave];
    unsigned short* aggT = aggT_all[wave];

    uint4 w2f[4][4];
    float mb2c[4];
    load_w2_folded(msg_w2, msg_gs1, msg_gb1, msg_gs2, msg_b2, msg_gb2,
                   g, lrow, lgrp, w2f, mb2c);

    const char* ycell = (const char*)yws + (size_t)n * C_N * 256;

    for (int ci = 0; ci < 16; ++ci) {
        int gidx = base + ci;
        float attreg = attw[(size_t)gidx * 64 + lane];
        unsigned bep = *reinterpret_cast<const unsigned*>(
            (const char*)bews + (size_t)gidx * 256 + lane * 4);
        float be0 = bflo(bep), be1 = bfhi(bep);
        int jv = conn_idx[(size_t)gidx * 16 + lrow];
        float p0 = 0.f, p1 = 0.f, p2 = 0.f, p3 = 0.f,
              p4 = 0.f, p5 = 0.f, p6 = 0.f, p7 = 0.f;
        #pragma unroll
        for (int k = 0; k < 16; ++k) {
            int j = __builtin_amdgcn_readlane(jv, k);
            unsigned u = *reinterpret_cast<const unsigned*>(ycell + (size_t)j * 256 + lane * 4);
            float g0 = gelu_f(bflo(u) + be0);
            float g1 = gelu_f(bfhi(u) + be1);
            float a0 = rl(attreg, k),      a1 = rl(attreg, 16 + k);
            float a2 = rl(attreg, 32 + k), a3 = rl(attreg, 48 + k);
            p0 = fmaf(a0, g0, p0); p1 = fmaf(a0, g1, p1);
            p2 = fmaf(a1, g0, p2); p3 = fmaf(a1, g1, p3);
            p4 = fmaf(a2, g0, p4); p5 = fmaf(a2, g1, p5);
            p6 = fmaf(a3, g0, p6); p7 = fmaf(a3, g1, p7);
        }
        unsigned pk0 = cvtpk(p0, p1), pk1 = cvtpk(p2, p3),
                 pk2 = cvtpk(p4, p5), pk3 = cvtpk(p6, p7);
        int swz = (lane * 4) ^ ((ci & 7) << 4);
        char* pb = reinterpret_cast<char*>(pbuf);
        *reinterpret_cast<unsigned*>(pb + (0 * 16 + ci) * 256 + swz) = pk0;
        *reinterpret_cast<unsigned*>(pb + (1 * 16 + ci) * 256 + swz) = pk1;
        *reinterpret_cast<unsigned*>(pb + (2 * 16 + ci) * 256 + swz) = pk2;
        *reinterpret_cast<unsigned*>(pb + (3 * 16 + ci) * 256 + swz) = pk3;
    }

    // L2: per head t, [16c][128q] x w2f[:,t-block] -> [16c][16d]
    #pragma unroll
    for (int t = 0; t < 4; ++t) {
        f32x4v acc = {0.f, 0.f, 0.f, 0.f};
        #pragma unroll
        for (int kf = 0; kf < 4; ++kf) {
            uint4 a = *reinterpret_cast<const uint4*>(
                reinterpret_cast<const char*>(pbuf) +
                (t * 16 + lrow) * 256 + ((kf * 64 + lgrp * 16) ^ ((lrow & 7) << 4)));
            acc = mfma16(a, w2f[t][kf], acc);
        }
        #pragma unroll
        for (int r = 0; r < 4; ++r) {
            float v = acc[r] + mb2c[t];
            int c = lgrp * 4 + r;
            int byte = c * 128 + ((((t * 16 + lrow)) * 2) ^ ((c & 7) << 4));
            *reinterpret_cast<unsigned short*>(reinterpret_cast<char*>(aggT) + byte) = f2bf(v);
        }
    }
    #pragma unroll
    for (int pass = 0; pass < 2; ++pass) {
        int idx = pass * 64 + lane;
        int row = idx >> 3, col = idx & 7;
        int byte = row * 128 + ((col * 16) ^ ((row & 7) << 4));
        uint4 v = *reinterpret_cast<const uint4*>(reinterpret_cast<const char*>(aggT) + byte);
        *reinterpret_cast<uint4*>((char*)aggws + (size_t)(base + row) * 128 + col * 16) = v;
    }
}

// ---------- kernel 5: state MLP + residual ----------
// 256 blocks (half-cell) x 512 thr (8 waves x 16 neurons). state_w1 staged in
// LDS once; S1 swapped (A=w1 rows q, B=[h|agg] cols c); S2 with folded w2;
// delta transposed via LDS -> coalesced float4 out.

__global__ __launch_bounds__(512, 4) void state_kernel(
    const float* __restrict__ h, const unsigned short* __restrict__ aggws,
    const float* __restrict__ gatep,
    const float* __restrict__ state_w1, const float* __restrict__ state_b1,
    const float* __restrict__ state_gs1, const float* __restrict__ state_gb1,
    const float* __restrict__ state_w2, const float* __restrict__ state_b2,
    const float* __restrict__ state_gs2, const float* __restrict__ state_gb2,
    const int* __restrict__ cell_to_group, float* __restrict__ out)
{
    __shared__ __align__(16) unsigned short w1s[128 * 128];      // 32KB
    __shared__ __align__(16) unsigned short s1b_all[8][16 * 128]; // 4KB/wave
    int tid = threadIdx.x, bid = blockIdx.x;
    int n = bid >> 1;
    int g = cell_to_group[n];

    for (int idx = tid; idx < 2048; idx += 512) {
        int row = idx >> 4, ch = idx & 15;
        uint4 p = packf8(state_w1 + (size_t)row * 128 + ch * 8);
        int byte = row * 256 + ((ch * 16) ^ ((row & 7) << 4));
        *reinterpret_cast<uint4*>(reinterpret_cast<char*>(w1s) + byte) = p;
    }
    __syncthreads();

    int wave = tid >> 6, lane = tid & 63;
    int lrow = lane & 15, lgrp = lane >> 4;
    int c0 = (bid & 1) * 128 + wave * 16;
    unsigned short* s1b = s1b_all[wave];

    uint4 sB[4];
    {
        const float* hp = h + ((size_t)n * C_N + c0 + lrow) * 64;
        sB[0] = packf8(hp + lgrp * 8);
        sB[1] = packf8(hp + 32 + lgrp * 8);
        const char* ap = (const char*)aggws + ((size_t)n * C_N + c0 + lrow) * 128;
        sB[2] = *reinterpret_cast<const uint4*>(ap + lgrp * 16);
        sB[3] = *reinterpret_cast<const uint4*>(ap + 64 + lgrp * 16);
    }
    for (int nbM = 0; nbM < 8; ++nbM) {
        uint4 wA[4];
        #pragma unroll
        for (int kf = 0; kf < 4; ++kf)
            wA[kf] = *reinterpret_cast<const uint4*>(
                reinterpret_cast<const char*>(w1s) +
                (nbM * 16 + lrow) * 256 + ((kf * 64 + lgrp * 16) ^ ((lrow & 7) << 4)));
        f32x4v acc = {0.f, 0.f, 0.f, 0.f};
        #pragma unroll
        for (int kf = 0; kf < 4; ++kf) acc = mfma16(wA[kf], sB[kf], acc);
        float4 b1q = *(const float4*)(state_b1 + nbM * 16 + lgrp * 4);
        float g0 = gelu_f(acc[0] + b1q.x), g1 = gelu_f(acc[1] + b1q.y);
        float g2 = gelu_f(acc[2] + b1q.z), g3 = gelu_f(acc[3] + b1q.w);
        uint2 pk = make_uint2(cvtpk(g0, g1), cvtpk(g2, g3));
        int byte = lrow * 256 + ((nbM * 32 + lgrp * 8) ^ ((lrow & 7) << 4));
        *reinterpret_cast<uint2*>(reinterpret_cast<char*>(s1b) + byte) = pk;
    }

    uint4 w2sf[4][4];
    float sb2c[4];
    load_w2_folded(state_w2, state_gs1, state_gb1, state_gs2, state_b2, state_gb2,
                   g, lrow, lgrp, w2sf, sb2c);
    uint4 s1A[4];
    #pragma unroll
    for (int kf = 0; kf < 4; ++kf)
        s1A[kf] = *reinterpret_cast<const uint4*>(
            reinterpret_cast<const char*>(s1b) +
            lrow * 256 + ((kf * 64 + lgrp * 16) ^ ((lrow & 7) << 4)));

    float* dT = reinterpret_cast<float*>(s1b);   // reuse 4KB as [16c][64d] f32
    #pragma unroll
    for (int nb2 = 0; nb2 < 4; ++nb2) {
        f32x4v acc = {0.f, 0.f, 0.f, 0.f};
        #pragma unroll
        for (int kf = 0; kf < 4; ++kf) acc = mfma16(s1A[kf], w2sf[nb2][kf], acc);
        #pragma unroll
        for (int r = 0; r < 4; ++r) {
            int c = lgrp * 4 + r;
            int d = nb2 * 16 + lrow;
            int byte = c * 256 + ((d * 4) ^ ((c & 7) << 4));
            *reinterpret_cast<float*>(reinterpret_cast<char*>(dT) + byte) = acc[r] + sb2c[nb2];
        }
    }
    #pragma unroll
    for (int pass = 0; pass < 4; ++pass) {
        int idx = pass * 64 + lane;
        int row = idx >> 4, col = idx & 15;
        int byte = row * 256 + ((col * 16) ^ ((row & 7) << 4));
        float4 dv = *reinterpret_cast<const float4*>(reinterpret_cast<const char*>(dT) + byte);
        size_t off = ((size_t)n * C_N + c0 + row) * 64 + col * 4;
        float4 hv = *(const float4*)(h + off);
        float4 gv = *(const float4*)(gatep + n * 64 + col * 4);
        float4 o;
        o.x = fmaf(gv.x, dv.x, hv.x);
        o.y = fmaf(gv.y, dv.y, hv.y);
        o.z = fmaf(gv.z, dv.z, hv.z);
        o.w = fmaf(gv.w, dv.w, hv.w);
        *(float4*)(out + off) = o;
    }
}

// ---------- launch ----------

extern "C" void kernel_launch(void* const* d_in, const int* in_sizes, int n_in,
                              void* d_out, int out_size, void* d_ws, size_t ws_size,
                              hipStream_t stream) {
    (void)in_sizes; (void)n_in; (void)out_size; (void)ws_size;
    const float* h          = (const float*)d_in[0];
    const float* neuron_id  = (const float*)d_in[1];
    const float* neuron_key = (const float*)d_in[2];
    const float* state_w1   = (const float*)d_in[3];
    const float* state_b1   = (const float*)d_in[4];
    const float* state_gs1  = (const float*)d_in[5];
    const float* state_gb1  = (const float*)d_in[6];
    const float* state_w2   = (const float*)d_in[7];
    const float* state_b2   = (const float*)d_in[8];
    const float* state_gs2  = (const float*)d_in[9];
    const float* state_gb2  = (const float*)d_in[10];
    const float* msg_w1     = (const float*)d_in[11];
    const float* msg_b1     = (const float*)d_in[12];
    const float* msg_gs1    = (const float*)d_in[13];
    const float* msg_gb1    = (const float*)d_in[14];
    const float* msg_w2     = (const float*)d_in[15];
    const float* msg_b2     = (const float*)d_in[16];
    const float* msg_gs2    = (const float*)d_in[17];
    const float* msg_gb2    = (const float*)d_in[18];
    const float* mod_w1     = (const float*)d_in[19];
    const float* mod_b1     = (const float*)d_in[20];
    const float* mod_w2     = (const float*)d_in[21];
    const float* mod_b2     = (const float*)d_in[22];
    const int*   conn_idx   = (const int*)d_in[23];
    const int*   c2g        = (const int*)d_in[24];

    char* ws = (char*)d_ws;
    float*          gatep = (float*)ws;                                      // 32 KB
    unsigned short* yws   = (unsigned short*)(ws + (32u << 10));             // 8 MB
    unsigned short* bews  = (unsigned short*)(ws + (32u << 10) + (8u << 20));  // 8 MB
    float*          attws = (float*)(ws + (32u << 10) + (16u << 20));          // 8 MB
    unsigned short* aggws = (unsigned short*)(ws + (32u << 10) + (24u << 20)); // 4 MB
    float* outp = (float*)d_out;

    gate_kernel<<<dim3(N_CELLS), dim3(1024), 0, stream>>>(
        h, mod_w1, mod_b1, mod_w2, mod_b2, gatep);
    node_kernel<<<dim3(256), dim3(512), 0, stream>>>(
        h, msg_w1, msg_b1, yws, bews);
    att_kernel<<<dim3(512), dim3(256), 0, stream>>>(
        neuron_id, neuron_key, conn_idx, attws);
    edge_kernel<<<dim3(512), dim3(256), 0, stream>>>(
        yws, bews, attws, conn_idx,
        msg_w2, msg_gs1, msg_gb1, msg_gs2, msg_b2, msg_gb2, c2g, aggws);
    state_kernel<<<dim3(256), dim3(512), 0, stream>>>(
        h, aggws, gatep,
        state_w1, state_b1, state_gs1, state_gb1,
        state_w2, state_b2, state_gs2, state_gb2, c2g, outp);
}

// Round 4
// 130.465 us; speedup vs baseline: 5.4639x; 1.2923x over previous
//
#include <hip/hip_runtime.h>
#include <hip/hip_bf16.h>

#define N_CELLS 128
#define C_N     256
#define K_NB    16
#define D_N     64
#define G_N     8
#define HS      128
#define HM      128
#define HMOD    64

typedef __bf16 bf16x8 __attribute__((ext_vector_type(8)));
typedef float  f32x4v __attribute__((ext_vector_type(4)));

// ---------- helpers ----------

__device__ __forceinline__ float rl(float v, int l) {
    return __uint_as_float((unsigned)__builtin_amdgcn_readlane((int)__float_as_uint(v), l));
}

__device__ __forceinline__ unsigned cvtpk(float lo, float hi) {
    __hip_bfloat162 t = __float22bfloat162_rn(float2{lo, hi});
    return *reinterpret_cast<unsigned*>(&t);
}

__device__ __forceinline__ unsigned short f2bf(float f) {
    return (unsigned short)(cvtpk(f, 0.f) & 0xffffu);
}

__device__ __forceinline__ float bflo(unsigned u) { return __uint_as_float(u << 16); }
__device__ __forceinline__ float bfhi(unsigned u) { return __uint_as_float(u & 0xffff0000u); }

__device__ __forceinline__ f32x4v mfma16(uint4 a, uint4 b, f32x4v c) {
    return __builtin_amdgcn_mfma_f32_16x16x32_bf16(
        __builtin_bit_cast(bf16x8, a), __builtin_bit_cast(bf16x8, b), c, 0, 0, 0);
}

__device__ __forceinline__ float gelu_f(float x) {
    float x2 = x * x;
    float u  = x * fmaf(x2, 0.044715f, 1.0f);
    float e  = __expf(1.5957691216057308f * u);
    float r  = __builtin_amdgcn_rcpf(e + 1.0f);
    return x - x * r;
}

__device__ __forceinline__ float tanh_fast(float z) {
    float e = __expf(2.0f * z);
    return 1.0f - 2.0f / (e + 1.0f);
}

__device__ __forceinline__ uint4 packf8(const float* p) {
    float4 a = *(const float4*)p, b = *(const float4*)(p + 4);
    return make_uint4(cvtpk(a.x, a.y), cvtpk(a.z, a.w), cvtpk(b.x, b.y), cvtpk(b.z, b.w));
}

// wf = gs2[d] * w2[d][k] * gs1[k];  c2 = gs2*(w2.gb1 + b2) + gb2   (verified R2)
__device__ __forceinline__ void load_w2_folded(
    const float* __restrict__ w2, const float* __restrict__ gs1,
    const float* __restrict__ gb1, const float* __restrict__ gs2,
    const float* __restrict__ b2, const float* __restrict__ gb2,
    int g, int lrow, int lgrp, uint4 wf[4][4], float c2[4])
{
    #pragma unroll
    for (int nb2 = 0; nb2 < 4; ++nb2) {
        int d = nb2 * 16 + lrow;
        float gs2d = gs2[g * 64 + d];
        float cgb = 0.0f;
        #pragma unroll
        for (int kf = 0; kf < 4; ++kf) {
            int k0 = kf * 32 + lgrp * 8;
            const float* wp = w2 + d * 128 + k0;
            float4 wa = *(const float4*)wp, wb = *(const float4*)(wp + 4);
            const float* gp = gs1 + g * 128 + k0;
            float4 ga = *(const float4*)gp, gbv = *(const float4*)(gp + 4);
            const float* bp = gb1 + g * 128 + k0;
            float4 ba = *(const float4*)bp, bbv = *(const float4*)(bp + 4);
            cgb += wa.x*ba.x + wa.y*ba.y + wa.z*ba.z + wa.w*ba.w
                 + wb.x*bbv.x + wb.y*bbv.y + wb.z*bbv.z + wb.w*bbv.w;
            wf[nb2][kf] = make_uint4(
                cvtpk(wa.x*ga.x*gs2d,  wa.y*ga.y*gs2d),
                cvtpk(wa.z*ga.z*gs2d,  wa.w*ga.w*gs2d),
                cvtpk(wb.x*gbv.x*gs2d, wb.y*gbv.y*gs2d),
                cvtpk(wb.z*gbv.z*gs2d, wb.w*gbv.w*gs2d));
        }
        cgb += __shfl_xor(cgb, 16);
        cgb += __shfl_xor(cgb, 32);
        c2[nb2] = fmaf(gs2d, cgb + b2[d], gb2[g * 64 + d]);
    }
}

// ---------- kernel 1: per-cell modulation gate ----------

__global__ __launch_bounds__(1024) void gate_kernel(
    const float* __restrict__ h,
    const float* __restrict__ mod_w1, const float* __restrict__ mod_b1,
    const float* __restrict__ mod_w2, const float* __restrict__ mod_b2,
    float* __restrict__ gatep)
{
    __shared__ float red[16][64];
    __shared__ float pooled[64];
    __shared__ float mh[64];
    int n = blockIdx.x, tid = threadIdx.x;
    int d = tid & 63, part = tid >> 6;
    const float* hn = h + (size_t)n * C_N * 64;
    float acc = 0.0f;
    #pragma unroll 4
    for (int i = 0; i < 16; ++i) acc += hn[(part * 16 + i) * 64 + d];
    red[part][d] = acc;
    __syncthreads();
    if (tid < 64) {
        float s = 0.0f;
        #pragma unroll
        for (int p = 0; p < 16; ++p) s += red[p][d];
        pooled[d] = s * (1.0f / 256.0f);
    }
    __syncthreads();
    if (tid < 64) {
        float a1 = mod_b1[n * HMOD + d];
        for (int q = 0; q < 64; ++q)
            a1 = fmaf(pooled[q], mod_w1[((size_t)n * 64 + q) * HMOD + d], a1);
        mh[d] = tanh_fast(a1);
    }
    __syncthreads();
    if (tid < 64) {
        float a2 = mod_b2[n * 64 + d];
        for (int q = 0; q < HMOD; ++q)
            a2 = fmaf(mh[q], mod_w2[((size_t)n * HMOD + q) * 64 + d], a2);
        gatep[n * 64 + d] = tanh_fast(a2);
    }
}

// ---------- kernel 2: per-node projections y = w1n.h, beffpb = w1h.h + b1 ----------

__global__ __launch_bounds__(512, 4) void node_kernel(
    const float* __restrict__ h, const float* __restrict__ msg_w1,
    const float* __restrict__ msg_b1,
    unsigned short* __restrict__ yws, unsigned short* __restrict__ bews)
{
    __shared__ __align__(16) unsigned short ybuf_all[8][16 * 256];  // 8KB/wave
    int tid = threadIdx.x, bid = blockIdx.x;
    int n = bid >> 1;
    int wave = tid >> 6, lane = tid & 63;
    int lrow = lane & 15, lgrp = lane >> 4;
    int c0 = (bid & 1) * 128 + wave * 16;
    unsigned short* ybuf = ybuf_all[wave];

    uint4 bf[2];
    {
        const float* hp = h + ((size_t)n * C_N + (c0 + lrow)) * 64;
        bf[0] = packf8(hp + lgrp * 8);
        bf[1] = packf8(hp + 32 + lgrp * 8);
    }
    for (int nbM = 0; nbM < 16; ++nbM) {
        int o = nbM * 16 + lrow;
        uint4 af[2];
        #pragma unroll
        for (int kf = 0; kf < 2; ++kf) {
            int k = kf * 32 + lgrp * 8;
            const float* wp = (o < 128) ? (msg_w1 + (size_t)o * 128 + k)
                                        : (msg_w1 + (size_t)(o - 128) * 128 + 64 + k);
            af[kf] = packf8(wp);
        }
        f32x4v acc = {0.f, 0.f, 0.f, 0.f};
        acc = mfma16(af[0], bf[0], acc);
        acc = mfma16(af[1], bf[1], acc);
        float4 addv = {0.f, 0.f, 0.f, 0.f};
        if (nbM >= 8) addv = *(const float4*)(msg_b1 + (nbM - 8) * 16 + lgrp * 4);
        uint2 pk = make_uint2(cvtpk(acc[0] + addv.x, acc[1] + addv.y),
                              cvtpk(acc[2] + addv.z, acc[3] + addv.w));
        int byte = lrow * 512 + ((nbM * 32 + lgrp * 8) ^ ((lrow & 7) << 4));
        *reinterpret_cast<uint2*>(reinterpret_cast<char*>(ybuf) + byte) = pk;
    }
    #pragma unroll
    for (int pass = 0; pass < 8; ++pass) {
        int idx = pass * 64 + lane;
        int row = idx >> 5, col = idx & 31;
        int byte = row * 512 + ((col * 16) ^ ((row & 7) << 4));
        uint4 v = *reinterpret_cast<const uint4*>(reinterpret_cast<const char*>(ybuf) + byte);
        size_t rb = (((size_t)n * C_N + c0 + row) * 128) * 2;
        if (col < 16)
            *reinterpret_cast<uint4*>(reinterpret_cast<char*>(yws) + rb + col * 16) = v;
        else
            *reinterpret_cast<uint4*>(reinterpret_cast<char*>(bews) + rb + (col - 16) * 16) = v;
    }
}

// ---------- kernel 3: attention weights ----------

__global__ __launch_bounds__(256, 4) void att_kernel(
    const float* __restrict__ neuron_id, const float* __restrict__ neuron_key,
    const int* __restrict__ conn_idx, float* __restrict__ attw)
{
    int tid = threadIdx.x, bid = blockIdx.x;
    int wave = tid >> 6, lane = tid & 63;
    int lrow = lane & 15, t = lane >> 4;
    int base = bid * 64 + wave * 16;

    for (int i = 0; i < 16; ++i) {
        int gidx = base + i;
        int jv = conn_idx[(size_t)gidx * 16 + lrow];
        const float* kp = neuron_id + ((size_t)(gidx & ~255) + jv) * 64 + t * 16;
        const float* qp = neuron_key + (size_t)gidx * 64 + t * 16;
        float4 k0 = *(const float4*)kp,       k1 = *(const float4*)(kp + 4),
               k2 = *(const float4*)(kp + 8), k3 = *(const float4*)(kp + 12);
        float4 q0 = *(const float4*)qp,       q1 = *(const float4*)(qp + 4),
               q2 = *(const float4*)(qp + 8), q3 = *(const float4*)(qp + 12);
        float dt = k0.x*q0.x + k0.y*q0.y + k0.z*q0.z + k0.w*q0.w
                 + k1.x*q1.x + k1.y*q1.y + k1.z*q1.z + k1.w*q1.w
                 + k2.x*q2.x + k2.y*q2.y + k2.z*q2.z + k2.w*q2.w
                 + k3.x*q3.x + k3.y*q3.y + k3.z*q3.z + k3.w*q3.w;
        float lg = dt * 0.25f;
        float mx = lg;
        mx = fmaxf(mx, __shfl_xor(mx, 1));
        mx = fmaxf(mx, __shfl_xor(mx, 2));
        mx = fmaxf(mx, __shfl_xor(mx, 4));
        mx = fmaxf(mx, __shfl_xor(mx, 8));
        float ex = __expf(lg - mx);
        float sm = ex;
        sm += __shfl_xor(sm, 1);
        sm += __shfl_xor(sm, 2);
        sm += __shfl_xor(sm, 4);
        sm += __shfl_xor(sm, 8);
        attw[(size_t)gidx * 64 + lane] = ex * __builtin_amdgcn_rcpf(sm);
    }
}

// ---------- kernel 4: edge phase (v2: 8 neurons/wave, high occupancy) ----------
// 1024 blocks x 256 thr (4 waves x 8 neurons). Per neuron: prefetch 16 y-rows
// (coalesced 256B u32/lane), gelu + attn-weighted accumulate p[t] in regs,
// transpose-write pbuf (8KB/wave). Then L2 mfma with folded w2 (loaded AFTER
// the gather loop to keep hot-loop VGPRs low), agg -> aggws via aggT LDS.

__global__ __launch_bounds__(256, 4) void edge_kernel(
    const unsigned short* __restrict__ yws, const unsigned short* __restrict__ bews,
    const float* __restrict__ attw, const int* __restrict__ conn_idx,
    const float* __restrict__ msg_w2, const float* __restrict__ msg_gs1,
    const float* __restrict__ msg_gb1, const float* __restrict__ msg_gs2,
    const float* __restrict__ msg_b2, const float* __restrict__ msg_gb2,
    const int* __restrict__ cell_to_group,
    unsigned short* __restrict__ aggws)
{
    __shared__ __align__(16) unsigned short pbuf_all[4][4 * 8 * 128];  // 8KB/wave
    __shared__ __align__(16) unsigned short aggT_all[4][8 * 64];       // 1KB/wave
    int tid = threadIdx.x, bid = blockIdx.x;
    int wave = tid >> 6, lane = tid & 63;
    int lrow = lane & 15, lgrp = lane >> 4;
    int base = bid * 32 + wave * 8;      // 8 neurons per wave, 32 per block
    int n = base >> 8;
    unsigned short* pbuf = pbuf_all[wave];
    unsigned short* aggT = aggT_all[wave];
    const char* ycell = (const char*)yws + (size_t)n * C_N * 256;

    for (int ci = 0; ci < 8; ++ci) {
        int gidx = base + ci;
        float attreg = attw[(size_t)gidx * 64 + lane];
        unsigned bep = *reinterpret_cast<const unsigned*>(
            (const char*)bews + (size_t)gidx * 256 + lane * 4);
        float be0 = bflo(bep), be1 = bfhi(bep);
        int jv = conn_idx[(size_t)gidx * 16 + lrow];
        // phase 1: issue all 16 independent gathers
        unsigned uy[16];
        #pragma unroll
        for (int k = 0; k < 16; ++k) {
            int j = __builtin_amdgcn_readlane(jv, k);
            uy[k] = *reinterpret_cast<const unsigned*>(ycell + (size_t)j * 256 + lane * 4);
        }
        // phase 2: gelu + attn-weighted accumulate
        float p0 = 0.f, p1 = 0.f, p2 = 0.f, p3 = 0.f,
              p4 = 0.f, p5 = 0.f, p6 = 0.f, p7 = 0.f;
        #pragma unroll
        for (int k = 0; k < 16; ++k) {
            float g0 = gelu_f(bflo(uy[k]) + be0);
            float g1 = gelu_f(bfhi(uy[k]) + be1);
            float a0 = rl(attreg, k),      a1 = rl(attreg, 16 + k);
            float a2 = rl(attreg, 32 + k), a3 = rl(attreg, 48 + k);
            p0 = fmaf(a0, g0, p0); p1 = fmaf(a0, g1, p1);
            p2 = fmaf(a1, g0, p2); p3 = fmaf(a1, g1, p3);
            p4 = fmaf(a2, g0, p4); p5 = fmaf(a2, g1, p5);
            p6 = fmaf(a3, g0, p6); p7 = fmaf(a3, g1, p7);
        }
        unsigned pk0 = cvtpk(p0, p1), pk1 = cvtpk(p2, p3),
                 pk2 = cvtpk(p4, p5), pk3 = cvtpk(p6, p7);
        int swz = (lane * 4) ^ ((ci & 7) << 4);
        char* pb = reinterpret_cast<char*>(pbuf);
        *reinterpret_cast<unsigned*>(pb + (0 * 8 + ci) * 256 + swz) = pk0;
        *reinterpret_cast<unsigned*>(pb + (1 * 8 + ci) * 256 + swz) = pk1;
        *reinterpret_cast<unsigned*>(pb + (2 * 8 + ci) * 256 + swz) = pk2;
        *reinterpret_cast<unsigned*>(pb + (3 * 8 + ci) * 256 + swz) = pk3;
    }

    // ---- L2 (folded w2 loaded only now, after the hot loop) ----
    uint4 w2f[4][4];
    float mb2c[4];
    int g = cell_to_group[n];
    load_w2_folded(msg_w2, msg_gs1, msg_gb1, msg_gs2, msg_b2, msg_gb2,
                   g, lrow, lgrp, w2f, mb2c);

    int arow = lrow & 7;   // A rows 8-15 duplicate 0-7 (same-address broadcast, free)
    #pragma unroll
    for (int t = 0; t < 4; ++t) {
        f32x4v acc = {0.f, 0.f, 0.f, 0.f};
        #pragma unroll
        for (int kf = 0; kf < 4; ++kf) {
            uint4 a = *reinterpret_cast<const uint4*>(
                reinterpret_cast<const char*>(pbuf) +
                (t * 8 + arow) * 256 + ((kf * 64 + lgrp * 16) ^ (arow << 4)));
            acc = mfma16(a, w2f[t][kf], acc);
        }
        if (lgrp < 2) {
            #pragma unroll
            for (int r = 0; r < 4; ++r) {
                float v = acc[r] + mb2c[t];
                int c = lgrp * 4 + r;   // 0..7 valid
                int byte = c * 128 + ((((t * 16 + lrow)) * 2) ^ ((c & 7) << 4));
                *reinterpret_cast<unsigned short*>(reinterpret_cast<char*>(aggT) + byte) = f2bf(v);
            }
        }
    }
    {
        int row = lane >> 3, col = lane & 7;
        int byte = row * 128 + ((col * 16) ^ ((row & 7) << 4));
        uint4 v = *reinterpret_cast<const uint4*>(reinterpret_cast<const char*>(aggT) + byte);
        *reinterpret_cast<uint4*>((char*)aggws + (size_t)(base + row) * 128 + col * 16) = v;
    }
}

// ---------- kernel 5: state MLP + residual ----------

__global__ __launch_bounds__(512, 4) void state_kernel(
    const float* __restrict__ h, const unsigned short* __restrict__ aggws,
    const float* __restrict__ gatep,
    const float* __restrict__ state_w1, const float* __restrict__ state_b1,
    const float* __restrict__ state_gs1, const float* __restrict__ state_gb1,
    const float* __restrict__ state_w2, const float* __restrict__ state_b2,
    const float* __restrict__ state_gs2, const float* __restrict__ state_gb2,
    const int* __restrict__ cell_to_group, float* __restrict__ out)
{
    __shared__ __align__(16) unsigned short w1s[128 * 128];      // 32KB
    __shared__ __align__(16) unsigned short s1b_all[8][16 * 128]; // 4KB/wave
    int tid = threadIdx.x, bid = blockIdx.x;
    int n = bid >> 1;
    int g = cell_to_group[n];

    for (int idx = tid; idx < 2048; idx += 512) {
        int row = idx >> 4, ch = idx & 15;
        uint4 p = packf8(state_w1 + (size_t)row * 128 + ch * 8);
        int byte = row * 256 + ((ch * 16) ^ ((row & 7) << 4));
        *reinterpret_cast<uint4*>(reinterpret_cast<char*>(w1s) + byte) = p;
    }
    __syncthreads();

    int wave = tid >> 6, lane = tid & 63;
    int lrow = lane & 15, lgrp = lane >> 4;
    int c0 = (bid & 1) * 128 + wave * 16;
    unsigned short* s1b = s1b_all[wave];

    uint4 sB[4];
    {
        const float* hp = h + ((size_t)n * C_N + c0 + lrow) * 64;
        sB[0] = packf8(hp + lgrp * 8);
        sB[1] = packf8(hp + 32 + lgrp * 8);
        const char* ap = (const char*)aggws + ((size_t)n * C_N + c0 + lrow) * 128;
        sB[2] = *reinterpret_cast<const uint4*>(ap + lgrp * 16);
        sB[3] = *reinterpret_cast<const uint4*>(ap + 64 + lgrp * 16);
    }
    for (int nbM = 0; nbM < 8; ++nbM) {
        uint4 wA[4];
        #pragma unroll
        for (int kf = 0; kf < 4; ++kf)
            wA[kf] = *reinterpret_cast<const uint4*>(
                reinterpret_cast<const char*>(w1s) +
                (nbM * 16 + lrow) * 256 + ((kf * 64 + lgrp * 16) ^ ((lrow & 7) << 4)));
        f32x4v acc = {0.f, 0.f, 0.f, 0.f};
        #pragma unroll
        for (int kf = 0; kf < 4; ++kf) acc = mfma16(wA[kf], sB[kf], acc);
        float4 b1q = *(const float4*)(state_b1 + nbM * 16 + lgrp * 4);
        float g0 = gelu_f(acc[0] + b1q.x), g1 = gelu_f(acc[1] + b1q.y);
        float g2 = gelu_f(acc[2] + b1q.z), g3 = gelu_f(acc[3] + b1q.w);
        uint2 pk = make_uint2(cvtpk(g0, g1), cvtpk(g2, g3));
        int byte = lrow * 256 + ((nbM * 32 + lgrp * 8) ^ ((lrow & 7) << 4));
        *reinterpret_cast<uint2*>(reinterpret_cast<char*>(s1b) + byte) = pk;
    }

    uint4 w2sf[4][4];
    float sb2c[4];
    load_w2_folded(state_w2, state_gs1, state_gb1, state_gs2, state_b2, state_gb2,
                   g, lrow, lgrp, w2sf, sb2c);
    uint4 s1A[4];
    #pragma unroll
    for (int kf = 0; kf < 4; ++kf)
        s1A[kf] = *reinterpret_cast<const uint4*>(
            reinterpret_cast<const char*>(s1b) +
            lrow * 256 + ((kf * 64 + lgrp * 16) ^ ((lrow & 7) << 4)));

    float* dT = reinterpret_cast<float*>(s1b);   // reuse 4KB as [16c][64d] f32
    #pragma unroll
    for (int nb2 = 0; nb2 < 4; ++nb2) {
        f32x4v acc = {0.f, 0.f, 0.f, 0.f};
        #pragma unroll
        for (int kf = 0; kf < 4; ++kf) acc = mfma16(s1A[kf], w2sf[nb2][kf], acc);
        #pragma unroll
        for (int r = 0; r < 4; ++r) {
            int c = lgrp * 4 + r;
            int d = nb2 * 16 + lrow;
            int byte = c * 256 + ((d * 4) ^ ((c & 7) << 4));
            *reinterpret_cast<float*>(reinterpret_cast<char*>(dT) + byte) = acc[r] + sb2c[nb2];
        }
    }
    #pragma unroll
    for (int pass = 0; pass < 4; ++pass) {
        int idx = pass * 64 + lane;
        int row = idx >> 4, col = idx & 15;
        int byte = row * 256 + ((col * 16) ^ ((row & 7) << 4));
        float4 dv = *reinterpret_cast<const float4*>(reinterpret_cast<const char*>(dT) + byte);
        size_t off = ((size_t)n * C_N + c0 + row) * 64 + col * 4;
        float4 hv = *(const float4*)(h + off);
        float4 gv = *(const float4*)(gatep + n * 64 + col * 4);
        float4 o;
        o.x = fmaf(gv.x, dv.x, hv.x);
        o.y = fmaf(gv.y, dv.y, hv.y);
        o.z = fmaf(gv.z, dv.z, hv.z);
        o.w = fmaf(gv.w, dv.w, hv.w);
        *(float4*)(out + off) = o;
    }
}

// ---------- launch ----------

extern "C" void kernel_launch(void* const* d_in, const int* in_sizes, int n_in,
                              void* d_out, int out_size, void* d_ws, size_t ws_size,
                              hipStream_t stream) {
    (void)in_sizes; (void)n_in; (void)out_size; (void)ws_size;
    const float* h          = (const float*)d_in[0];
    const float* neuron_id  = (const float*)d_in[1];
    const float* neuron_key = (const float*)d_in[2];
    const float* state_w1   = (const float*)d_in[3];
    const float* state_b1   = (const float*)d_in[4];
    const float* state_gs1  = (const float*)d_in[5];
    const float* state_gb1  = (const float*)d_in[6];
    const float* state_w2   = (const float*)d_in[7];
    const float* state_b2   = (const float*)d_in[8];
    const float* state_gs2  = (const float*)d_in[9];
    const float* state_gb2  = (const float*)d_in[10];
    const float* msg_w1     = (const float*)d_in[11];
    const float* msg_b1     = (const float*)d_in[12];
    const float* msg_gs1    = (const float*)d_in[13];
    const float* msg_gb1    = (const float*)d_in[14];
    const float* msg_w2     = (const float*)d_in[15];
    const float* msg_b2     = (const float*)d_in[16];
    const float* msg_gs2    = (const float*)d_in[17];
    const float* msg_gb2    = (const float*)d_in[18];
    const float* mod_w1     = (const float*)d_in[19];
    const float* mod_b1     = (const float*)d_in[20];
    const float* mod_w2     = (const float*)d_in[21];
    const float* mod_b2     = (const float*)d_in[22];
    const int*   conn_idx   = (const int*)d_in[23];
    const int*   c2g        = (const int*)d_in[24];

    char* ws = (char*)d_ws;
    float*          gatep = (float*)ws;                                      // 32 KB
    unsigned short* yws   = (unsigned short*)(ws + (32u << 10));             // 8 MB
    unsigned short* bews  = (unsigned short*)(ws + (32u << 10) + (8u << 20));  // 8 MB
    float*          attws = (float*)(ws + (32u << 10) + (16u << 20));          // 8 MB
    unsigned short* aggws = (unsigned short*)(ws + (32u << 10) + (24u << 20)); // 4 MB
    float* outp = (float*)d_out;

    gate_kernel<<<dim3(N_CELLS), dim3(1024), 0, stream>>>(
        h, mod_w1, mod_b1, mod_w2, mod_b2, gatep);
    node_kernel<<<dim3(256), dim3(512), 0, stream>>>(
        h, msg_w1, msg_b1, yws, bews);
    att_kernel<<<dim3(512), dim3(256), 0, stream>>>(
        neuron_id, neuron_key, conn_idx, attws);
    edge_kernel<<<dim3(1024), dim3(256), 0, stream>>>(
        yws, bews, attws, conn_idx,
        msg_w2, msg_gs1, msg_gb1, msg_gs2, msg_b2, msg_gb2, c2g, aggws);
    state_kernel<<<dim3(256), dim3(512), 0, stream>>>(
        h, aggws, gatep,
        state_w1, state_b1, state_gs1, state_gb1,
        state_w2, state_b2, state_gs2, state_gb2, c2g, outp);
}